// Round 2
// baseline (458.644 us; speedup 1.0000x reference)
//
#include <hip/hip_runtime.h>
#include <hip/hip_bf16.h>
#include <stdint.h>

#ifndef DRNL
#define DRNL 64
#define HDIM 256
#endif

typedef __attribute__((ext_vector_type(4))) float f32x4;      // MFMA C/D
typedef __attribute__((ext_vector_type(8))) _Float16 f16x8;   // 16B fp16 / MFMA A,B

// ---------------------------------------------------------------------------
// helpers
// ---------------------------------------------------------------------------
// async 16B global -> LDS (lds dest must be wave-uniform-base + lane*16)
__device__ __forceinline__ void async16(void* lds, const void* g) {
    __builtin_amdgcn_global_load_lds(
        (const __attribute__((address_space(1))) void*)g,
        (__attribute__((address_space(3))) void*)(char*)lds, 16, 0, 0);
}

__device__ __forceinline__ int imin(int a, int b) { return a < b ? a : b; }

// ---------------------------------------------------------------------------
// k_misc: all order-independent prep in ONE launch (no grid.sync needed):
// zero(indeg+cursor), prepW3 (f32 -> transposed fp16), prepX, bounds.
// ---------------------------------------------------------------------------
__global__ __launch_bounds__(256) void k_misc(
    const int* __restrict__ batch,
    const float* __restrict__ x,
    const float* __restrict__ W0, const float* __restrict__ W1,
    const float* __restrict__ W2,
    int* __restrict__ indeg,          // zeroes 2N ints (indeg + cursor)
    int* __restrict__ gstart,
    _Float16* __restrict__ x16,
    _Float16* __restrict__ W0t, _Float16* __restrict__ W1t,
    _Float16* __restrict__ W2t,
    int N, int B) {
    const int gsz = gridDim.x * 256;
    const int gid0 = blockIdx.x * 256 + threadIdx.x;

    for (int i = gid0; i < 2 * N; i += gsz) indeg[i] = 0;

    for (int i = gid0; i < (DRNL + 2 * HDIM) * 256; i += gsz) {
        int b = i >> 8, c = i & 255;
        const float* W; _Float16* T; int k, K;
        if (b < DRNL)            { W = W0; T = W0t; k = b;              K = DRNL; }
        else if (b < DRNL + 256) { W = W1; T = W1t; k = b - DRNL;       K = HDIM; }
        else                     { W = W2; T = W2t; k = b - DRNL - 256; K = HDIM; }
        T[(size_t)c * K + k] = (_Float16)W[(size_t)k * 256 + c];
    }

    for (int i = gid0; i < N * DRNL; i += gsz) x16[i] = (_Float16)x[i];

    for (int i = gid0; i <= N; i += gsz) {
        if (i == 0) {
            int b0 = batch[0];
            for (int b = 0; b <= b0; ++b) gstart[b] = 0;
        } else if (i == N) {
            int bl = batch[N - 1];
            for (int b = bl + 1; b <= B; ++b) gstart[b] = N;
        } else {
            int bp = batch[i - 1], bc = batch[i];
            if (bc != bp)
                for (int b = bp + 1; b <= bc; ++b) gstart[b] = i;
        }
    }
}

// ---------------------------------------------------------------------------
// degree count (in-degree from dst)
// ---------------------------------------------------------------------------
__global__ __launch_bounds__(256) void k_count_indeg(const int* __restrict__ dst,
                                                     int* __restrict__ indeg, int E) {
    int e = blockIdx.x * 256 + threadIdx.x;
    if (e < E) atomicAdd(&indeg[dst[e]], 1);
}

// ---------------------------------------------------------------------------
// exclusive scan of indeg -> rowptr (also emits dis = rsqrt(indeg+1))
// ---------------------------------------------------------------------------
__global__ __launch_bounds__(256) void k_scan1(const int* __restrict__ in,
                                               int* __restrict__ out,
                                               int* __restrict__ partial,
                                               float* __restrict__ dis, int n) {
    __shared__ int s[256];
    int tid = threadIdx.x;
    int i = blockIdx.x * 256 + tid;
    int v = (i < n) ? in[i] : 0;
    if (i < n) dis[i] = rsqrtf((float)(v + 1));
    s[tid] = v;
    __syncthreads();
    for (int off = 1; off < 256; off <<= 1) {
        int t = (tid >= off) ? s[tid - off] : 0;
        __syncthreads();
        s[tid] += t;
        __syncthreads();
    }
    if (i < n) out[i] = s[tid] - v;
    if (tid == 255) partial[blockIdx.x] = s[255];
}

__global__ __launch_bounds__(256) void k_scan2(int* __restrict__ partial, int nb,
                                               int* __restrict__ rowptr, int n, int total) {
    __shared__ int s[256];
    int tid = threadIdx.x;
    int v = (tid < nb) ? partial[tid] : 0;
    s[tid] = v;
    __syncthreads();
    for (int off = 1; off < 256; off <<= 1) {
        int t = (tid >= off) ? s[tid - off] : 0;
        __syncthreads();
        s[tid] += t;
        __syncthreads();
    }
    if (tid < nb) partial[tid] = s[tid] - v;
    if (tid == 0) rowptr[n] = total;
}

__global__ __launch_bounds__(256) void k_scan3(int* __restrict__ rowptr,
                                               const int* __restrict__ partial, int n) {
    int i = blockIdx.x * 256 + threadIdx.x;
    if (i < n) rowptr[i] += partial[blockIdx.x];
}

// ---------------------------------------------------------------------------
// CSR fill (counting sort by dst)
// ---------------------------------------------------------------------------
__global__ __launch_bounds__(256) void k_fill(const int* __restrict__ src,
                                              const int* __restrict__ dst,
                                              const int* __restrict__ rowptr,
                                              int* __restrict__ cursor,
                                              int* __restrict__ col, int E) {
    int e = blockIdx.x * 256 + threadIdx.x;
    if (e < E) {
        int d = dst[e];
        int pos = atomicAdd(&cursor[d], 1);
        col[rowptr[d] + pos] = src[e];
    }
}

// ---------------------------------------------------------------------------
// Aggregation, 64-wide (layer 0): 8 lanes x 16B per edge row -> 8 edges/step
// writes fp16 A in blocked-32 layout [2][N][32]
// ---------------------------------------------------------------------------
__global__ __launch_bounds__(256) void k_agg64(const _Float16* __restrict__ x16,
                                               const float* __restrict__ dis,
                                               const int* __restrict__ rowptr,
                                               const int* __restrict__ col,
                                               _Float16* __restrict__ A16, int N) {
    int gw = (blockIdx.x * 256 + threadIdx.x) >> 6;
    int lane = threadIdx.x & 63;
    if (gw >= N) return;
    int g = lane >> 3;      // edge group 0..7
    int fl = lane & 7;      // feature chunk (8 feats = 16B)
    const f16x8* hv = (const f16x8*)x16;   // 8 chunks per row
    float acc[8];
#pragma unroll
    for (int k = 0; k < 8; ++k) acc[k] = 0.f;

    int e0 = rowptr[gw], e1 = rowptr[gw + 1];
    int j = e0 + g;
    for (; j + 8 < e1; j += 16) {
        int s0 = col[j], s1 = col[j + 8];
        float w0 = dis[s0], w1 = dis[s1];
        f16x8 v0 = hv[(size_t)s0 * 8 + fl];
        f16x8 v1 = hv[(size_t)s1 * 8 + fl];
#pragma unroll
        for (int k = 0; k < 8; ++k) acc[k] += w0 * (float)v0[k];
#pragma unroll
        for (int k = 0; k < 8; ++k) acc[k] += w1 * (float)v1[k];
    }
    for (; j < e1; j += 8) {
        int s = col[j];
        float w = dis[s];
        f16x8 v = hv[(size_t)s * 8 + fl];
#pragma unroll
        for (int k = 0; k < 8; ++k) acc[k] += w * (float)v[k];
    }
    // reduce across the 8 edge groups (lanes fl, fl+8, ..., fl+56)
#pragma unroll
    for (int m = 8; m < 64; m <<= 1)
#pragma unroll
        for (int k = 0; k < 8; ++k) acc[k] += __shfl_xor(acc[k], m);

    float dn = dis[gw];
    f16x8 hs = hv[(size_t)gw * 8 + fl];
    f16x8 o;
#pragma unroll
    for (int k = 0; k < 8; ++k)
        o[k] = (_Float16)((acc[k] + dn * (float)hs[k]) * dn);
    // blocked-32 write: feature f0 = fl*8 -> block fl>>2, within (fl&3)*8
    if (g == 0)
        __builtin_nontemporal_store(
            o, (f16x8*)(A16 + (size_t)(fl >> 2) * ((size_t)N * 32) +
                        (size_t)gw * 32 + (fl & 3) * 8));
}

// ---------------------------------------------------------------------------
// Aggregation over blocked layout [8][N][32]: one 3.2 MB feature block per
// XCD (fits 4 MB L2) via blockIdx%8 -> XCD round-robin (validated r1: fetch
// 188->108 MB). Each 4-lane quartet walks its OWN node's edge list serially:
// no cross-lane reduce, per-node overhead amortized (r1's failure was 4x
// wave duplication of the reduce tree at avg deg 16). 16 nodes/wave, 64/WG.
// Inactive quartets predicated with w=0. Non-temporal A-store keeps the
// gather block L2-resident.
// ---------------------------------------------------------------------------
__global__ __launch_bounds__(256) void k_aggown(const _Float16* __restrict__ h16,
                                                const float* __restrict__ dis,
                                                const int* __restrict__ rowptr,
                                                const int* __restrict__ col,
                                                _Float16* __restrict__ A16, int N) {
    int wg = blockIdx.x;
    int f = wg & 7;              // feature block == XCD
    int nodeWG = wg >> 3;        // 64 nodes per WG
    int lane = threadIdx.x & 63;
    int wv = threadIdx.x >> 6;   // wave 0..3
    int qt = lane >> 2;          // quartet 0..15 -> own node
    int fl = lane & 3;           // feature chunk (8 feats = 16B)
    int gw = nodeWG * 64 + wv * 16 + qt;
    bool valid = gw < N;
    int gwc = valid ? gw : N - 1;
    const size_t boff = (size_t)f * ((size_t)N * 32);
    const f16x8* hv = (const f16x8*)(h16 + boff);   // 4 chunks per blocked row
    float acc[8];
#pragma unroll
    for (int k = 0; k < 8; ++k) acc[k] = 0.f;

    int e0 = rowptr[gwc];
    int e1 = valid ? rowptr[gwc + 1] : e0;
    int j = e0;
    while (__any(j < e1)) {
        bool a0 = j < e1;
        bool a1 = j + 1 < e1;
        int jj0 = a0 ? j : 0;
        int jj1 = a1 ? j + 1 : 0;
        int s0 = col[jj0];
        int s1 = col[jj1];
        float w0 = a0 ? dis[s0] : 0.f;
        float w1 = a1 ? dis[s1] : 0.f;
        f16x8 v0 = hv[(size_t)s0 * 4 + fl];
        f16x8 v1 = hv[(size_t)s1 * 4 + fl];
#pragma unroll
        for (int k = 0; k < 8; ++k) acc[k] += w0 * (float)v0[k];
#pragma unroll
        for (int k = 0; k < 8; ++k) acc[k] += w1 * (float)v1[k];
        j += 2;
    }

    float dn = dis[gwc];
    f16x8 hs = hv[(size_t)gwc * 4 + fl];
    f16x8 o;
#pragma unroll
    for (int k = 0; k < 8; ++k)
        o[k] = (_Float16)((acc[k] + dn * (float)hs[k]) * dn);
    if (valid)
        __builtin_nontemporal_store(
            o, (f16x8*)(A16 + boff + (size_t)gw * 32 + fl * 8));
}

// ---------------------------------------------------------------------------
// fp16 MFMA GEMM: out = A@W + bias.  A blocked [(K/32)][n][32] fp16;
// W [256][K] fp16; out blocked [8][n][32].
// Block 128 rows x 256 cols, 4 waves. 1 MFMA/16x16 tile. LDS 24 KB.
// Feature ORDER is preserved (only storage strided), so W is unchanged.
// ---------------------------------------------------------------------------
template <int K, int OUT_RELU>
__global__ __launch_bounds__(256, 2) void k_mgemm(const _Float16* __restrict__ A,
                                                  const _Float16* __restrict__ W,
                                                  const float* __restrict__ bias,
                                                  _Float16* __restrict__ outh, int n) {
    __shared__ _Float16 sA[128 * 32];   // 8 KB
    __shared__ _Float16 sW[256 * 32];   // 16 KB

    const int tid = threadIdx.x;
    const int lane = tid & 63;
    const int w = tid >> 6;
    const int c15 = lane & 15;
    const int q = lane >> 4;
    const int row0 = blockIdx.x * 128;
    const size_t bstride = (size_t)n * 32;   // feature-block stride

    f32x4 acc[8][4];
#pragma unroll
    for (int i = 0; i < 8; ++i)
#pragma unroll
        for (int j = 0; j < 4; ++j) acc[i][j] = (f32x4)0.f;

    for (int kt = 0; kt < K; kt += 32) {
        // ---- stage A: 512 16B-units (blocked-32 source: one block per kt) ----
        const _Float16* Ab = A + (size_t)(kt >> 5) * bstride;
#pragma unroll
        for (int i = 0; i < 2; ++i) {
            int u = tid + (i << 8);
            int row = u >> 2;
            int qq = (u & 3) ^ ((row >> 1) & 3);
            int r = imin(row0 + row, n - 1);
            size_t goff = (size_t)r * 32 + qq * 8;
            async16(sA + u * 8, Ab + goff);
        }
        // ---- stage W: 1024 16B-units ----
#pragma unroll
        for (int i = 0; i < 4; ++i) {
            int u = tid + (i << 8);
            int c = u >> 2;
            int qq = (u & 3) ^ ((c >> 1) & 3);
            size_t goff = (size_t)c * K + kt + qq * 8;
            async16(sW + u * 8, W + goff);
        }
        __syncthreads();

        f16x8 wf[4];
#pragma unroll
        for (int ct = 0; ct < 4; ++ct) {
            int c = (w << 6) + (ct << 4) + c15;
            int u = (c << 2) + (q ^ ((c >> 1) & 3));
            wf[ct] = *(const f16x8*)(sW + u * 8);
        }
#pragma unroll
        for (int rt = 0; rt < 8; ++rt) {
            int r = (rt << 4) + c15;
            int u = (r << 2) + (q ^ ((r >> 1) & 3));
            f16x8 a = *(const f16x8*)(sA + u * 8);
#pragma unroll
            for (int ct = 0; ct < 4; ++ct)
                acc[rt][ct] = __builtin_amdgcn_mfma_f32_16x16x32_f16(a, wf[ct], acc[rt][ct], 0, 0, 0);
        }
        __syncthreads();
    }

    // ---- epilogue: C/D layout col=lane&15, row=(lane>>4)*4+reg ----
    // blocked-32 write: outh[(c>>5)][row][c&31]
#pragma unroll
    for (int ct = 0; ct < 4; ++ct) {
        int c = (w << 6) + (ct << 4) + c15;
        float bv = bias[c];
        _Float16* ob = outh + (size_t)(c >> 5) * bstride + (c & 31);
#pragma unroll
        for (int rt = 0; rt < 8; ++rt) {
#pragma unroll
            for (int r = 0; r < 4; ++r) {
                int row = row0 + (rt << 4) + (q << 2) + r;
                if (row < n) {
                    float v = acc[rt][ct][r] + bv;
                    if (OUT_RELU) v = fmaxf(v, 0.f);
                    ob[(size_t)row * 32] = (_Float16)v;
                }
            }
        }
    }
}

// ---------------------------------------------------------------------------
// fused head: mean-pool + concat + MLP -> out[b]. one block per graph.
// h is blocked [8][N][32]: element (i, t) at h[(t>>5)*N*32 + i*32 + (t&31)].
// ---------------------------------------------------------------------------
__global__ __launch_bounds__(256) void k_head(const _Float16* __restrict__ h,
                                              const int* __restrict__ gstart,
                                              const int* __restrict__ u,
                                              const int* __restrict__ v,
                                              const float* __restrict__ Wm1,
                                              const float* __restrict__ bm1,
                                              const float* __restrict__ Wm2,
                                              const float* __restrict__ bm2,
                                              float* __restrict__ out, int N) {
    int b = blockIdx.x;
    int t = threadIdx.x;
    __shared__ float z[3 * HDIM];
    __shared__ float red[4];
    const _Float16* hb = h + (size_t)(t >> 5) * ((size_t)N * 32) + (t & 31);
    // mean pool, 4 rows in flight
    int s = gstart[b], e = gstart[b + 1];
    float pa = 0.f;
    int i = s;
    for (; i + 3 < e; i += 4) {
        float a0 = (float)hb[(size_t)i * 32];
        float a1 = (float)hb[(size_t)(i + 1) * 32];
        float a2 = (float)hb[(size_t)(i + 2) * 32];
        float a3 = (float)hb[(size_t)(i + 3) * 32];
        pa += (a0 + a1) + (a2 + a3);
    }
    for (; i < e; ++i) pa += (float)hb[(size_t)i * 32];
    z[t]            = pa / fmaxf((float)(e - s), 1.f);
    z[HDIM + t]     = (float)hb[(size_t)u[b] * 32];
    z[2 * HDIM + t] = (float)hb[(size_t)v[b] * 32];
    __syncthreads();
    // MLP, 8 independent chains
    float acc[8];
#pragma unroll
    for (int k = 0; k < 8; ++k) acc[k] = 0.f;
    for (int k = 0; k < 3 * HDIM; k += 8) {
#pragma unroll
        for (int jj = 0; jj < 8; ++jj)
            acc[jj] = fmaf(z[k + jj], Wm1[(size_t)(k + jj) * HDIM + t], acc[jj]);
    }
    float sum = (((acc[0] + acc[1]) + (acc[2] + acc[3])) +
                 ((acc[4] + acc[5]) + (acc[6] + acc[7]))) + bm1[t];
    float hid = fmaxf(sum, 0.f);
    float p = hid * Wm2[t];
    for (int off = 32; off; off >>= 1) p += __shfl_down(p, off);
    if ((t & 63) == 0) red[t >> 6] = p;
    __syncthreads();
    if (t == 0) out[b] = red[0] + red[1] + red[2] + red[3] + bm2[0];
}

// ---------------------------------------------------------------------------
extern "C" void kernel_launch(void* const* d_in, const int* in_sizes, int n_in,
                              void* d_out, int out_size, void* d_ws, size_t ws_size,
                              hipStream_t stream) {
    const float* x    = (const float*)d_in[0];
    const int*   ei   = (const int*)d_in[1];
    const int*   batc = (const int*)d_in[2];
    const int*   uidx = (const int*)d_in[3];
    const int*   vidx = (const int*)d_in[4];
    const float* W0   = (const float*)d_in[5];
    const float* b0   = (const float*)d_in[6];
    const float* W1   = (const float*)d_in[7];
    const float* b1   = (const float*)d_in[8];
    const float* W2   = (const float*)d_in[9];
    const float* b2   = (const float*)d_in[10];
    const float* Wm1  = (const float*)d_in[11];
    const float* bm1  = (const float*)d_in[12];
    const float* Wm2  = (const float*)d_in[13];
    const float* bm2  = (const float*)d_in[14];
    float* out = (float*)d_out;

    const int N = in_sizes[0] / DRNL;
    const int E = in_sizes[1] / 2;
    const int B = in_sizes[3];
    const int* src = ei;
    const int* dst = ei + E;

    char* w = (char*)d_ws;
    size_t off = 0;
    auto carve = [&](size_t bytes) {
        void* p = w + off;
        off = (off + bytes + 255) & ~(size_t)255;
        return p;
    };
    // indeg and cursor carved as ONE block (zeroed together in k_misc)
    int*       indeg  = (int*)carve((size_t)N * 8);
    int*       cursor = indeg + N;
    int*       rowptr = (int*)carve((size_t)(N + 1) * 4);
    int*       part   = (int*)carve(256 * 4);
    int*       colA   = (int*)carve((size_t)E * 4);
    float*     dis    = (float*)carve((size_t)N * 4);
    int*       gstart = (int*)carve((size_t)(B + 1) * 4);
    _Float16*  A16    = (_Float16*)carve((size_t)N * HDIM * 2);
    _Float16*  h16    = (_Float16*)carve((size_t)N * HDIM * 2);
    _Float16*  x16    = (_Float16*)carve((size_t)N * DRNL * 2);
    _Float16*  W0t    = (_Float16*)carve((size_t)DRNL * HDIM * 2);
    _Float16*  W1t    = (_Float16*)carve((size_t)HDIM * HDIM * 2);
    _Float16*  W2t    = (_Float16*)carve((size_t)HDIM * HDIM * 2);
    (void)ws_size;

    int eb = (E + 255) / 256;
    int nb = (N + 255) / 256;

    // one launch for all order-independent prep (zero, prepW, prepX, bounds)
    k_misc<<<1024, 256, 0, stream>>>(batc, x, W0, W1, W2, indeg, gstart,
                                     x16, W0t, W1t, W2t, N, B);
    // CSR chain (true dependencies)
    k_count_indeg<<<eb, 256, 0, stream>>>(dst, indeg, E);
    k_scan1<<<nb, 256, 0, stream>>>(indeg, rowptr, part, dis, N);
    k_scan2<<<1, 256, 0, stream>>>(part, nb, rowptr, N, E);
    k_scan3<<<nb, 256, 0, stream>>>(rowptr, part, N);
    k_fill<<<eb, 256, 0, stream>>>(src, dst, rowptr, cursor, colA, E);

    int aggb = (N + 3) / 4;
    int gemmb = (N + 127) / 128;
    int aggob = 8 * ((N + 63) / 64);   // 8 feature blocks x node WGs

    // layer 0: agg(x16) -> GEMM -> h16 (relu, blocked)
    k_agg64<<<aggb, 256, 0, stream>>>(x16, dis, rowptr, colA, A16, N);
    k_mgemm<DRNL, 1><<<gemmb, 256, 0, stream>>>(A16, W0t, b0, h16, N);
    // layer 1: blocked agg(h16) -> GEMM -> h16 (relu, blocked)
    k_aggown<<<aggob, 256, 0, stream>>>(h16, dis, rowptr, colA, A16, N);
    k_mgemm<HDIM, 1><<<gemmb, 256, 0, stream>>>(A16, W1t, b1, h16, N);
    // layer 2: blocked agg(h16) -> GEMM -> h16 (no relu, blocked)
    k_aggown<<<aggob, 256, 0, stream>>>(h16, dis, rowptr, colA, A16, N);
    k_mgemm<HDIM, 0><<<gemmb, 256, 0, stream>>>(A16, W2t, b2, h16, N);

    // fused mean-pool + MLP head
    k_head<<<B, 256, 0, stream>>>(h16, gstart, uidx, vidx, Wm1, bm1, Wm2, bm2, out, N);
}

// Round 3
// 384.211 us; speedup vs baseline: 1.1937x; 1.1937x over previous
//
#include <hip/hip_runtime.h>
#include <hip/hip_bf16.h>
#include <stdint.h>

#ifndef DRNL
#define DRNL 64
#define HDIM 256
#endif

typedef __attribute__((ext_vector_type(4))) float f32x4;      // MFMA C/D
typedef __attribute__((ext_vector_type(8))) _Float16 f16x8;   // 16B fp16 / MFMA A,B

// ---------------------------------------------------------------------------
// helpers
// ---------------------------------------------------------------------------
// async 16B global -> LDS (lds dest must be wave-uniform-base + lane*16)
__device__ __forceinline__ void async16(void* lds, const void* g) {
    __builtin_amdgcn_global_load_lds(
        (const __attribute__((address_space(1))) void*)g,
        (__attribute__((address_space(3))) void*)(char*)lds, 16, 0, 0);
}

__device__ __forceinline__ int imin(int a, int b) { return a < b ? a : b; }

// ---------------------------------------------------------------------------
// k_misc: all order-independent prep in ONE launch (no grid.sync needed):
// zero(indeg+cursor), prepW3 (f32 -> transposed fp16), prepX, bounds.
// ---------------------------------------------------------------------------
__global__ __launch_bounds__(256) void k_misc(
    const int* __restrict__ batch,
    const float* __restrict__ x,
    const float* __restrict__ W0, const float* __restrict__ W1,
    const float* __restrict__ W2,
    int* __restrict__ indeg,          // zeroes 2N ints (indeg + cursor)
    int* __restrict__ gstart,
    _Float16* __restrict__ x16,
    _Float16* __restrict__ W0t, _Float16* __restrict__ W1t,
    _Float16* __restrict__ W2t,
    int N, int B) {
    const int gsz = gridDim.x * 256;
    const int gid0 = blockIdx.x * 256 + threadIdx.x;

    for (int i = gid0; i < 2 * N; i += gsz) indeg[i] = 0;

    for (int i = gid0; i < (DRNL + 2 * HDIM) * 256; i += gsz) {
        int b = i >> 8, c = i & 255;
        const float* W; _Float16* T; int k, K;
        if (b < DRNL)            { W = W0; T = W0t; k = b;              K = DRNL; }
        else if (b < DRNL + 256) { W = W1; T = W1t; k = b - DRNL;       K = HDIM; }
        else                     { W = W2; T = W2t; k = b - DRNL - 256; K = HDIM; }
        T[(size_t)c * K + k] = (_Float16)W[(size_t)k * 256 + c];
    }

    for (int i = gid0; i < N * DRNL; i += gsz) x16[i] = (_Float16)x[i];

    for (int i = gid0; i <= N; i += gsz) {
        if (i == 0) {
            int b0 = batch[0];
            for (int b = 0; b <= b0; ++b) gstart[b] = 0;
        } else if (i == N) {
            int bl = batch[N - 1];
            for (int b = bl + 1; b <= B; ++b) gstart[b] = N;
        } else {
            int bp = batch[i - 1], bc = batch[i];
            if (bc != bp)
                for (int b = bp + 1; b <= bc; ++b) gstart[b] = i;
        }
    }
}

// ---------------------------------------------------------------------------
// degree count (in-degree from dst)
// ---------------------------------------------------------------------------
__global__ __launch_bounds__(256) void k_count_indeg(const int* __restrict__ dst,
                                                     int* __restrict__ indeg, int E) {
    int e = blockIdx.x * 256 + threadIdx.x;
    if (e < E) atomicAdd(&indeg[dst[e]], 1);
}

// ---------------------------------------------------------------------------
// exclusive scan of indeg -> rowptr (also emits dis = rsqrt(indeg+1))
// ---------------------------------------------------------------------------
__global__ __launch_bounds__(256) void k_scan1(const int* __restrict__ in,
                                               int* __restrict__ out,
                                               int* __restrict__ partial,
                                               float* __restrict__ dis, int n) {
    __shared__ int s[256];
    int tid = threadIdx.x;
    int i = blockIdx.x * 256 + tid;
    int v = (i < n) ? in[i] : 0;
    if (i < n) dis[i] = rsqrtf((float)(v + 1));
    s[tid] = v;
    __syncthreads();
    for (int off = 1; off < 256; off <<= 1) {
        int t = (tid >= off) ? s[tid - off] : 0;
        __syncthreads();
        s[tid] += t;
        __syncthreads();
    }
    if (i < n) out[i] = s[tid] - v;
    if (tid == 255) partial[blockIdx.x] = s[255];
}

__global__ __launch_bounds__(256) void k_scan2(int* __restrict__ partial, int nb,
                                               int* __restrict__ rowptr, int n, int total) {
    __shared__ int s[256];
    int tid = threadIdx.x;
    int v = (tid < nb) ? partial[tid] : 0;
    s[tid] = v;
    __syncthreads();
    for (int off = 1; off < 256; off <<= 1) {
        int t = (tid >= off) ? s[tid - off] : 0;
        __syncthreads();
        s[tid] += t;
        __syncthreads();
    }
    if (tid < nb) partial[tid] = s[tid] - v;
    if (tid == 0) rowptr[n] = total;
}

// scan3 + in-place prescale of x16 by dis (x' = x*dis, enables weightless agg)
__global__ __launch_bounds__(256) void k_scan3x(int* __restrict__ rowptr,
                                                const int* __restrict__ partial,
                                                const float* __restrict__ dis,
                                                _Float16* __restrict__ x16, int n) {
    int i = blockIdx.x * 256 + threadIdx.x;
    if (i < n) rowptr[i] += partial[blockIdx.x];
    // grid-stride over n*8 16B-chunks of x16
    f16x8* xv = (f16x8*)x16;
    int tot = n * 8;
    int gsz = gridDim.x * 256;
    for (int c = blockIdx.x * 256 + threadIdx.x; c < tot; c += gsz) {
        float d = dis[c >> 3];
        f16x8 v = xv[c];
        f16x8 o;
#pragma unroll
        for (int k = 0; k < 8; ++k) o[k] = (_Float16)((float)v[k] * d);
        xv[c] = o;
    }
}

// ---------------------------------------------------------------------------
// CSR fill (counting sort by dst)
// ---------------------------------------------------------------------------
__global__ __launch_bounds__(256) void k_fill(const int* __restrict__ src,
                                              const int* __restrict__ dst,
                                              const int* __restrict__ rowptr,
                                              int* __restrict__ cursor,
                                              int* __restrict__ col, int E) {
    int e = blockIdx.x * 256 + threadIdx.x;
    if (e < E) {
        int d = dst[e];
        int pos = atomicAdd(&cursor[d], 1);
        col[rowptr[d] + pos] = src[e];
    }
}

// ---------------------------------------------------------------------------
// Aggregation over PRE-SCALED rows h' = h*dis, blocked-64 layout [FBLK][N][64].
// agg[dst] = dis[dst] * (sum_{src} h'[src] + h'[dst])  == exact GCN agg.
// Each 8-lane OCTET owns one node and walks its edge list serially:
//  - no per-edge dis gather, no weight multiply (algebraic elimination)
//  - one full 128B cache line per edge row request (8 lanes x 16B)
//  - no cross-lane reduce
// FBLK=4: feature block f pinned to XCD pair {2f,2f+1} via blockIdx%8 round-
// robin (r1-validated); nodes split across the pair halves.
// FBLK=1: layer 0 (x', 64 feats, single block), grid = node WGs.
// 32 nodes/WG. Unroll 4 edges for MLP; inactive slots masked with m=0.
// ---------------------------------------------------------------------------
template <int FBLK>
__global__ __launch_bounds__(256) void k_agg(const _Float16* __restrict__ hs,
                                             const float* __restrict__ dis,
                                             const int* __restrict__ rowptr,
                                             const int* __restrict__ col,
                                             _Float16* __restrict__ A16, int N) {
    int node_wg, f;
    if constexpr (FBLK == 4) {
        int wg = blockIdx.x;
        int xcd = wg & 7;            // dispatch round-robins blockIdx across XCDs
        f = xcd >> 1;                // feature block -> XCD pair
        int half = xcd & 1;
        int NH = gridDim.x >> 3;     // node-WGs per half
        node_wg = half * NH + (wg >> 3);
    } else {
        node_wg = blockIdx.x;
        f = 0;
    }
    int lane = threadIdx.x & 63;
    int wv = threadIdx.x >> 6;   // wave 0..3
    int oct = lane >> 3;         // octet 0..7 -> own node
    int fl = lane & 7;           // feature chunk (8 feats = 16B)
    int gw = node_wg * 32 + wv * 8 + oct;
    bool valid = gw < N;
    int gwc = valid ? gw : N - 1;
    const size_t boff = (size_t)f * ((size_t)N * 64);
    const f16x8* hv = (const f16x8*)(hs + boff);   // 8 chunks per blocked row
    float acc[8];
#pragma unroll
    for (int k = 0; k < 8; ++k) acc[k] = 0.f;

    int e0 = rowptr[gwc];
    int e1 = valid ? rowptr[gwc + 1] : e0;
    int j = e0;
    while (__any(j < e1)) {
        bool a0 = j < e1, a1 = j + 1 < e1, a2 = j + 2 < e1, a3 = j + 3 < e1;
        int s0 = col[a0 ? j : 0];
        int s1 = col[a1 ? j + 1 : 0];
        int s2 = col[a2 ? j + 2 : 0];
        int s3 = col[a3 ? j + 3 : 0];
        float m0 = a0 ? 1.f : 0.f, m1 = a1 ? 1.f : 0.f;
        float m2 = a2 ? 1.f : 0.f, m3 = a3 ? 1.f : 0.f;
        f16x8 v0 = hv[(size_t)s0 * 8 + fl];
        f16x8 v1 = hv[(size_t)s1 * 8 + fl];
        f16x8 v2 = hv[(size_t)s2 * 8 + fl];
        f16x8 v3 = hv[(size_t)s3 * 8 + fl];
#pragma unroll
        for (int k = 0; k < 8; ++k) acc[k] += m0 * (float)v0[k];
#pragma unroll
        for (int k = 0; k < 8; ++k) acc[k] += m1 * (float)v1[k];
#pragma unroll
        for (int k = 0; k < 8; ++k) acc[k] += m2 * (float)v2[k];
#pragma unroll
        for (int k = 0; k < 8; ++k) acc[k] += m3 * (float)v3[k];
        j += 4;
    }

    float dn = dis[gwc];
    f16x8 hsv = hv[(size_t)gwc * 8 + fl];   // self term (already scaled)
    f16x8 o;
#pragma unroll
    for (int k = 0; k < 8; ++k)
        o[k] = (_Float16)((acc[k] + (float)hsv[k]) * dn);
    if (valid)
        __builtin_nontemporal_store(
            o, (f16x8*)(A16 + boff + (size_t)gw * 64 + fl * 8));
}

// ---------------------------------------------------------------------------
// fp16 MFMA GEMM: out = A@W + bias.  A blocked [(K/64)][n][64] fp16
// (degenerates to [n][K] for K=64); W [256][K] fp16; out blocked [4][n][64].
// Block 128 rows x 256 cols, 4 waves. 1 MFMA/16x16 tile. LDS 24 KB.
// SCALE: multiply output row by dis[row] (pre-scale for next agg layer).
// Feature ORDER is preserved (only storage strided), so W is unchanged.
// ---------------------------------------------------------------------------
template <int K, int OUT_RELU, int SCALE>
__global__ __launch_bounds__(256, 2) void k_mgemm(const _Float16* __restrict__ A,
                                                  const _Float16* __restrict__ W,
                                                  const float* __restrict__ bias,
                                                  const float* __restrict__ dis,
                                                  _Float16* __restrict__ outh, int n) {
    __shared__ _Float16 sA[128 * 32];   // 8 KB
    __shared__ _Float16 sW[256 * 32];   // 16 KB

    const int tid = threadIdx.x;
    const int lane = tid & 63;
    const int w = tid >> 6;
    const int c15 = lane & 15;
    const int q = lane >> 4;
    const int row0 = blockIdx.x * 128;
    const size_t bstride = (size_t)n * 64;   // feature-block stride

    f32x4 acc[8][4];
#pragma unroll
    for (int i = 0; i < 8; ++i)
#pragma unroll
        for (int j = 0; j < 4; ++j) acc[i][j] = (f32x4)0.f;

    for (int kt = 0; kt < K; kt += 32) {
        // ---- stage A: 512 16B-units (blocked-64 source) ----
#pragma unroll
        for (int i = 0; i < 2; ++i) {
            int u = tid + (i << 8);
            int row = u >> 2;
            int qq = (u & 3) ^ ((row >> 1) & 3);
            int r = imin(row0 + row, n - 1);
            size_t goff = (size_t)(kt >> 6) * bstride + (size_t)r * 64 + (kt & 63) + qq * 8;
            async16(sA + u * 8, A + goff);
        }
        // ---- stage W: 1024 16B-units ----
#pragma unroll
        for (int i = 0; i < 4; ++i) {
            int u = tid + (i << 8);
            int c = u >> 2;
            int qq = (u & 3) ^ ((c >> 1) & 3);
            size_t goff = (size_t)c * K + kt + qq * 8;
            async16(sW + u * 8, W + goff);
        }
        __syncthreads();

        f16x8 wf[4];
#pragma unroll
        for (int ct = 0; ct < 4; ++ct) {
            int c = (w << 6) + (ct << 4) + c15;
            int u = (c << 2) + (q ^ ((c >> 1) & 3));
            wf[ct] = *(const f16x8*)(sW + u * 8);
        }
#pragma unroll
        for (int rt = 0; rt < 8; ++rt) {
            int r = (rt << 4) + c15;
            int u = (r << 2) + (q ^ ((r >> 1) & 3));
            f16x8 a = *(const f16x8*)(sA + u * 8);
#pragma unroll
            for (int ct = 0; ct < 4; ++ct)
                acc[rt][ct] = __builtin_amdgcn_mfma_f32_16x16x32_f16(a, wf[ct], acc[rt][ct], 0, 0, 0);
        }
        __syncthreads();
    }

    // ---- epilogue: C/D layout col=lane&15, row=(lane>>4)*4+reg ----
    // blocked-64 write: outh[(c>>6)][row][c&63]
#pragma unroll
    for (int ct = 0; ct < 4; ++ct) {
        int c = (w << 6) + (ct << 4) + c15;
        float bv = bias[c];
        _Float16* ob = outh + (size_t)(c >> 6) * bstride + (c & 63);
#pragma unroll
        for (int rt = 0; rt < 8; ++rt) {
#pragma unroll
            for (int r = 0; r < 4; ++r) {
                int row = row0 + (rt << 4) + (q << 2) + r;
                if (row < n) {
                    float v = acc[rt][ct][r] + bv;
                    if (OUT_RELU) v = fmaxf(v, 0.f);
                    if (SCALE) v *= dis[row];
                    ob[(size_t)row * 64] = (_Float16)v;
                }
            }
        }
    }
}

// ---------------------------------------------------------------------------
// fused head: mean-pool + concat + MLP -> out[b]. one block per graph.
// h is blocked [4][N][64]: element (i, t) at h[(t>>6)*N*64 + i*64 + (t&63)].
// ---------------------------------------------------------------------------
__global__ __launch_bounds__(256) void k_head(const _Float16* __restrict__ h,
                                              const int* __restrict__ gstart,
                                              const int* __restrict__ u,
                                              const int* __restrict__ v,
                                              const float* __restrict__ Wm1,
                                              const float* __restrict__ bm1,
                                              const float* __restrict__ Wm2,
                                              const float* __restrict__ bm2,
                                              float* __restrict__ out, int N) {
    int b = blockIdx.x;
    int t = threadIdx.x;
    __shared__ float z[3 * HDIM];
    __shared__ float red[4];
    const _Float16* hb = h + (size_t)(t >> 6) * ((size_t)N * 64) + (t & 63);
    // mean pool, 4 rows in flight
    int s = gstart[b], e = gstart[b + 1];
    float pa = 0.f;
    int i = s;
    for (; i + 3 < e; i += 4) {
        float a0 = (float)hb[(size_t)i * 64];
        float a1 = (float)hb[(size_t)(i + 1) * 64];
        float a2 = (float)hb[(size_t)(i + 2) * 64];
        float a3 = (float)hb[(size_t)(i + 3) * 64];
        pa += (a0 + a1) + (a2 + a3);
    }
    for (; i < e; ++i) pa += (float)hb[(size_t)i * 64];
    z[t]            = pa / fmaxf((float)(e - s), 1.f);
    z[HDIM + t]     = (float)hb[(size_t)u[b] * 64];
    z[2 * HDIM + t] = (float)hb[(size_t)v[b] * 64];
    __syncthreads();
    // MLP, 8 independent chains
    float acc[8];
#pragma unroll
    for (int k = 0; k < 8; ++k) acc[k] = 0.f;
    for (int k = 0; k < 3 * HDIM; k += 8) {
#pragma unroll
        for (int jj = 0; jj < 8; ++jj)
            acc[jj] = fmaf(z[k + jj], Wm1[(size_t)(k + jj) * HDIM + t], acc[jj]);
    }
    float sum = (((acc[0] + acc[1]) + (acc[2] + acc[3])) +
                 ((acc[4] + acc[5]) + (acc[6] + acc[7]))) + bm1[t];
    float hid = fmaxf(sum, 0.f);
    float p = hid * Wm2[t];
    for (int off = 32; off; off >>= 1) p += __shfl_down(p, off);
    if ((t & 63) == 0) red[t >> 6] = p;
    __syncthreads();
    if (t == 0) out[b] = red[0] + red[1] + red[2] + red[3] + bm2[0];
}

// ---------------------------------------------------------------------------
extern "C" void kernel_launch(void* const* d_in, const int* in_sizes, int n_in,
                              void* d_out, int out_size, void* d_ws, size_t ws_size,
                              hipStream_t stream) {
    const float* x    = (const float*)d_in[0];
    const int*   ei   = (const int*)d_in[1];
    const int*   batc = (const int*)d_in[2];
    const int*   uidx = (const int*)d_in[3];
    const int*   vidx = (const int*)d_in[4];
    const float* W0   = (const float*)d_in[5];
    const float* b0   = (const float*)d_in[6];
    const float* W1   = (const float*)d_in[7];
    const float* b1   = (const float*)d_in[8];
    const float* W2   = (const float*)d_in[9];
    const float* b2   = (const float*)d_in[10];
    const float* Wm1  = (const float*)d_in[11];
    const float* bm1  = (const float*)d_in[12];
    const float* Wm2  = (const float*)d_in[13];
    const float* bm2  = (const float*)d_in[14];
    float* out = (float*)d_out;

    const int N = in_sizes[0] / DRNL;
    const int E = in_sizes[1] / 2;
    const int B = in_sizes[3];
    const int* src = ei;
    const int* dst = ei + E;

    char* w = (char*)d_ws;
    size_t off = 0;
    auto carve = [&](size_t bytes) {
        void* p = w + off;
        off = (off + bytes + 255) & ~(size_t)255;
        return p;
    };
    // indeg and cursor carved as ONE block (zeroed together in k_misc)
    int*       indeg  = (int*)carve((size_t)N * 8);
    int*       cursor = indeg + N;
    int*       rowptr = (int*)carve((size_t)(N + 1) * 4);
    int*       part   = (int*)carve(256 * 4);
    int*       colA   = (int*)carve((size_t)E * 4);
    float*     dis    = (float*)carve((size_t)N * 4);
    int*       gstart = (int*)carve((size_t)(B + 1) * 4);
    _Float16*  A16    = (_Float16*)carve((size_t)N * HDIM * 2);
    _Float16*  h16    = (_Float16*)carve((size_t)N * HDIM * 2);
    _Float16*  x16    = (_Float16*)carve((size_t)N * DRNL * 2);
    _Float16*  W0t    = (_Float16*)carve((size_t)DRNL * HDIM * 2);
    _Float16*  W1t    = (_Float16*)carve((size_t)HDIM * HDIM * 2);
    _Float16*  W2t    = (_Float16*)carve((size_t)HDIM * HDIM * 2);
    (void)ws_size;

    int eb = (E + 255) / 256;
    int nb = (N + 255) / 256;

    // one launch for all order-independent prep (zero, prepW, prepX, bounds)
    k_misc<<<1024, 256, 0, stream>>>(batc, x, W0, W1, W2, indeg, gstart,
                                     x16, W0t, W1t, W2t, N, B);
    // CSR chain (true dependencies); scan3 also prescales x16 by dis
    k_count_indeg<<<eb, 256, 0, stream>>>(dst, indeg, E);
    k_scan1<<<nb, 256, 0, stream>>>(indeg, rowptr, part, dis, N);
    k_scan2<<<1, 256, 0, stream>>>(part, nb, rowptr, N, E);
    k_scan3x<<<nb, 256, 0, stream>>>(rowptr, part, dis, x16, N);
    k_fill<<<eb, 256, 0, stream>>>(src, dst, rowptr, cursor, colA, E);

    int gemmb = (N + 127) / 128;
    int NB = (N + 31) / 32;        // node-WGs (32 nodes each)
    int NH = (NB + 1) / 2;         // node-WGs per XCD-pair half
    int aggb4 = 8 * NH;            // FBLK=4 grid (multiple of 8)

    // layer 0: agg(x') -> GEMM (relu, scale) -> h' blocked-64
    k_agg<1><<<NB, 256, 0, stream>>>(x16, dis, rowptr, colA, A16, N);
    k_mgemm<DRNL, 1, 1><<<gemmb, 256, 0, stream>>>(A16, W0t, b0, dis, h16, N);
    // layer 1: agg(h') -> GEMM (relu, scale) -> h'
    k_agg<4><<<aggb4, 256, 0, stream>>>(h16, dis, rowptr, colA, A16, N);
    k_mgemm<HDIM, 1, 1><<<gemmb, 256, 0, stream>>>(A16, W1t, b1, dis, h16, N);
    // layer 2: agg(h') -> GEMM (no relu, RAW output for head)
    k_agg<4><<<aggb4, 256, 0, stream>>>(h16, dis, rowptr, colA, A16, N);
    k_mgemm<HDIM, 0, 0><<<gemmb, 256, 0, stream>>>(A16, W2t, b2, dis, h16, N);

    // fused mean-pool + MLP head
    k_head<<<B, 256, 0, stream>>>(h16, gstart, uidx, vidx, Wm1, bm1, Wm2, bm2, out, N);
}

// Round 4
// 335.635 us; speedup vs baseline: 1.3665x; 1.1447x over previous
//
#include <hip/hip_runtime.h>
#include <hip/hip_bf16.h>
#include <stdint.h>

#ifndef DRNL
#define DRNL 64
#define HDIM 256
#endif

#define CHUNK 4096      // edges per hist/scatter block
#define BCAP 3072       // LDS edge capacity per bucket (avg 2046, 22 sigma)

typedef __attribute__((ext_vector_type(4))) float f32x4;      // MFMA C/D
typedef __attribute__((ext_vector_type(8))) _Float16 f16x8;   // 16B fp16 / MFMA A,B

// ---------------------------------------------------------------------------
// helpers
// ---------------------------------------------------------------------------
__device__ __forceinline__ void async16(void* lds, const void* g) {
    __builtin_amdgcn_global_load_lds(
        (const __attribute__((address_space(1))) void*)g,
        (__attribute__((address_space(3))) void*)(char*)lds, 16, 0, 0);
}

__device__ __forceinline__ int imin(int a, int b) { return a < b ? a : b; }

// ---------------------------------------------------------------------------
// k_misc: order-independent prep: prepW3 (f32 -> transposed fp16), prepX,
// graph bounds. (indeg/cursor zeroing gone — no global atomics anywhere now)
// ---------------------------------------------------------------------------
__global__ __launch_bounds__(256) void k_misc(
    const int* __restrict__ batch,
    const float* __restrict__ x,
    const float* __restrict__ W0, const float* __restrict__ W1,
    const float* __restrict__ W2,
    int* __restrict__ gstart,
    _Float16* __restrict__ x16,
    _Float16* __restrict__ W0t, _Float16* __restrict__ W1t,
    _Float16* __restrict__ W2t,
    int N, int B) {
    const int gsz = gridDim.x * 256;
    const int gid0 = blockIdx.x * 256 + threadIdx.x;

    for (int i = gid0; i < (DRNL + 2 * HDIM) * 256; i += gsz) {
        int b = i >> 8, c = i & 255;
        const float* W; _Float16* T; int k, K;
        if (b < DRNL)            { W = W0; T = W0t; k = b;              K = DRNL; }
        else if (b < DRNL + 256) { W = W1; T = W1t; k = b - DRNL;       K = HDIM; }
        else                     { W = W2; T = W2t; k = b - DRNL - 256; K = HDIM; }
        T[(size_t)c * K + k] = (_Float16)W[(size_t)k * 256 + c];
    }

    for (int i = gid0; i < N * DRNL; i += gsz) x16[i] = (_Float16)x[i];

    for (int i = gid0; i <= N; i += gsz) {
        if (i == 0) {
            int b0 = batch[0];
            for (int b = 0; b <= b0; ++b) gstart[b] = 0;
        } else if (i == N) {
            int bl = batch[N - 1];
            for (int b = bl + 1; b <= B; ++b) gstart[b] = N;
        } else {
            int bp = batch[i - 1], bc = batch[i];
            if (bc != bp)
                for (int b = bp + 1; b <= bc; ++b) gstart[b] = i;
        }
    }
}

// ---------------------------------------------------------------------------
// CSR build, atomic-free (replaces k_count_indeg + scans + k_fill whose
// 800K device-scope atomics + 4B random scatter cost ~80us; r3 counters:
// k_fill WRITE_SIZE 55MB for a 3.2MB output = partial-line flush from 8
// non-coherent L2s).
// Bucket = dst >> SH (128 nodes/bucket). All counting via LDS.
// ---------------------------------------------------------------------------
// Phase 1: per-chunk LDS histogram -> ghist[bucket][chunk]
__global__ __launch_bounds__(256) void k_hist(const int* __restrict__ dst,
                                              int* __restrict__ ghist,
                                              int E, int P, int SH, int NBUCK) {
    __shared__ int h[512];
    int tid = threadIdx.x, p = blockIdx.x;
    for (int i = tid; i < NBUCK; i += 256) h[i] = 0;
    __syncthreads();
    int e0 = p * CHUNK, e1 = imin(e0 + CHUNK, E);
    for (int e = e0 + tid; e < e1; e += 256)
        atomicAdd(&h[dst[e] >> SH], 1);          // LDS atomic
    __syncthreads();
    for (int b = tid; b < NBUCK; b += 256)
        ghist[(size_t)b * P + p] = h[b];
}

// Phase 2a: per-bucket exclusive scan over chunks (in place) + bucket totals
__global__ __launch_bounds__(256) void k_gbase(int* __restrict__ ghist,
                                               int* __restrict__ btot, int P) {
    __shared__ int s[256];
    int b = blockIdx.x, tid = threadIdx.x;
    int* row = ghist + (size_t)b * P;
    int carry = 0;
    for (int base = 0; base < P; base += 256) {
        int idx = base + tid;
        int v = (idx < P) ? row[idx] : 0;
        s[tid] = v;
        __syncthreads();
        for (int o = 1; o < 256; o <<= 1) {
            int t = (tid >= o) ? s[tid - o] : 0;
            __syncthreads();
            s[tid] += t;
            __syncthreads();
        }
        if (idx < P) row[idx] = carry + s[tid] - v;
        carry += s[255];
        __syncthreads();
    }
    if (tid == 0) btot[b] = carry;
}

// Phase 2b: exclusive scan of bucket totals -> bbase; also rowptr[N]=E
__global__ __launch_bounds__(256) void k_btscan(const int* __restrict__ btot,
                                                int* __restrict__ bbase,
                                                int* __restrict__ rowptr,
                                                int NBUCK, int N, int E) {
    __shared__ int s[256];
    int tid = threadIdx.x;
    int carry = 0;
    for (int base = 0; base < NBUCK; base += 256) {
        int idx = base + tid;
        int v = (idx < NBUCK) ? btot[idx] : 0;
        s[tid] = v;
        __syncthreads();
        for (int o = 1; o < 256; o <<= 1) {
            int t = (tid >= o) ? s[tid - o] : 0;
            __syncthreads();
            s[tid] += t;
            __syncthreads();
        }
        if (idx < NBUCK) bbase[idx] = carry + s[tid] - v;
        carry += s[255];
        __syncthreads();
    }
    if (tid == 0) { bbase[NBUCK] = E; rowptr[N] = E; }
}

// Phase 3: scatter edges into bucket-grouped tmp, packed (src<<SH)|dstLow.
// LDS cursors only; writes are ~8-edge runs per bucket (line-friendly).
__global__ __launch_bounds__(256) void k_scatter(const int* __restrict__ src,
                                                 const int* __restrict__ dst,
                                                 const int* __restrict__ ghist,
                                                 const int* __restrict__ bbase,
                                                 int* __restrict__ tmp,
                                                 int E, int P, int SH, int NBUCK) {
    __shared__ int base[512];
    int p = blockIdx.x, tid = threadIdx.x;
    for (int b = tid; b < NBUCK; b += 256)
        base[b] = bbase[b] + ghist[(size_t)b * P + p];
    __syncthreads();
    int e0 = p * CHUNK, e1 = imin(e0 + CHUNK, E);
    int msk = (1 << SH) - 1;
    for (int e = e0 + tid; e < e1; e += 256) {
        int d = dst[e];
        int r = atomicAdd(&base[d >> SH], 1);    // LDS atomic = cursor
        tmp[r] = (src[e] << SH) | (d & msk);
    }
}

// Phase 4: per-bucket LDS counting sort -> col (coalesced write), plus
// rowptr, dis, and x16 prescale (x' = x*dis) for this bucket's nodes.
// bucket base in col == rowptr[node0] by construction (same totals).
__global__ __launch_bounds__(256) void k_bsort(const int* __restrict__ tmp,
                                               const int* __restrict__ bbase,
                                               int* __restrict__ col,
                                               int* __restrict__ rowptr,
                                               float* __restrict__ dis,
                                               _Float16* __restrict__ x16,
                                               int SH, int N) {
    __shared__ int cnt[512];
    __shared__ int off[512];
    __shared__ int sscan[256];
    __shared__ int eL[BCAP];
    __shared__ unsigned short rnk[BCAP];
    __shared__ int sL[BCAP];
    int b = blockIdx.x, tid = threadIdx.x;
    int nodes = 1 << SH, node0 = b << SH, msk = nodes - 1;
    int lo = bbase[b], hi = bbase[b + 1], m = hi - lo;
    bool fast = (m <= BCAP);

    for (int i = tid; i < nodes; i += 256) cnt[i] = 0;
    __syncthreads();
    if (fast) {
        for (int i = tid; i < m; i += 256) {
            int v = tmp[lo + i];
            eL[i] = v;
            rnk[i] = (unsigned short)atomicAdd(&cnt[v & msk], 1);
        }
    } else {
        for (int i = tid; i < m; i += 256)
            atomicAdd(&cnt[tmp[lo + i] & msk], 1);
    }
    __syncthreads();
    // exclusive scan cnt -> off
    int carry = 0;
    for (int base = 0; base < nodes; base += 256) {
        int idx = base + tid;
        int v = (idx < nodes) ? cnt[idx] : 0;
        sscan[tid] = v;
        __syncthreads();
        for (int o = 1; o < 256; o <<= 1) {
            int t = (tid >= o) ? sscan[tid - o] : 0;
            __syncthreads();
            sscan[tid] += t;
            __syncthreads();
        }
        if (idx < nodes) off[idx] = carry + sscan[tid] - v;
        carry += sscan[255];
        __syncthreads();
    }
    // rowptr + dis for this bucket's nodes
    for (int i = tid; i < nodes; i += 256) {
        int node = node0 + i;
        if (node < N) {
            rowptr[node] = lo + off[i];
            dis[node]    = rsqrtf((float)cnt[i] + 1.f);
        }
    }
    // x16 prescale (layer-0 input): 8 chunks of 16B per row
    int rlim = imin(nodes, N - node0);
    for (int u = tid; u < rlim * 8; u += 256) {
        int r = u >> 3, c = u & 7;
        float d = rsqrtf((float)cnt[r] + 1.f);
        f16x8* xv = (f16x8*)(x16 + (size_t)(node0 + r) * 64);
        f16x8 v = xv[c];
        f16x8 o;
#pragma unroll
        for (int k = 0; k < 8; ++k) o[k] = (_Float16)((float)v[k] * d);
        xv[c] = o;
    }
    __syncthreads();   // cnt must stay intact until here
    if (fast) {
        for (int i = tid; i < m; i += 256) {
            int v = eL[i];
            sL[off[v & msk] + rnk[i]] = v >> SH;
        }
        __syncthreads();
        for (int i = tid; i < m; i += 256) col[lo + i] = sL[i];
    } else {
        for (int i = tid; i < nodes; i += 256) cnt[i] = 0;
        __syncthreads();
        for (int i = tid; i < m; i += 256) {
            int v = tmp[lo + i];
            int d = v & msk;
            int r = atomicAdd(&cnt[d], 1);
            col[lo + off[d] + r] = v >> SH;
        }
    }
}

// ---------------------------------------------------------------------------
// Aggregation over PRE-SCALED rows h' = h*dis, blocked-64 layout [FBLK][N][64].
// agg[dst] = dis[dst] * (sum_{src} h'[src] + h'[dst])  == exact GCN agg.
// 8-lane octet owns one node; FBLK=4 pins feature block to XCD pair.
// ---------------------------------------------------------------------------
template <int FBLK>
__global__ __launch_bounds__(256) void k_agg(const _Float16* __restrict__ hs,
                                             const float* __restrict__ dis,
                                             const int* __restrict__ rowptr,
                                             const int* __restrict__ col,
                                             _Float16* __restrict__ A16, int N) {
    int node_wg, f;
    if constexpr (FBLK == 4) {
        int wg = blockIdx.x;
        int xcd = wg & 7;
        f = xcd >> 1;
        int half = xcd & 1;
        int NH = gridDim.x >> 3;
        node_wg = half * NH + (wg >> 3);
    } else {
        node_wg = blockIdx.x;
        f = 0;
    }
    int lane = threadIdx.x & 63;
    int wv = threadIdx.x >> 6;
    int oct = lane >> 3;
    int fl = lane & 7;
    int gw = node_wg * 32 + wv * 8 + oct;
    bool valid = gw < N;
    int gwc = valid ? gw : N - 1;
    const size_t boff = (size_t)f * ((size_t)N * 64);
    const f16x8* hv = (const f16x8*)(hs + boff);
    float acc[8];
#pragma unroll
    for (int k = 0; k < 8; ++k) acc[k] = 0.f;

    int e0 = rowptr[gwc];
    int e1 = valid ? rowptr[gwc + 1] : e0;
    int j = e0;
    while (__any(j < e1)) {
        bool a0 = j < e1, a1 = j + 1 < e1, a2 = j + 2 < e1, a3 = j + 3 < e1;
        int s0 = col[a0 ? j : 0];
        int s1 = col[a1 ? j + 1 : 0];
        int s2 = col[a2 ? j + 2 : 0];
        int s3 = col[a3 ? j + 3 : 0];
        float m0 = a0 ? 1.f : 0.f, m1 = a1 ? 1.f : 0.f;
        float m2 = a2 ? 1.f : 0.f, m3 = a3 ? 1.f : 0.f;
        f16x8 v0 = hv[(size_t)s0 * 8 + fl];
        f16x8 v1 = hv[(size_t)s1 * 8 + fl];
        f16x8 v2 = hv[(size_t)s2 * 8 + fl];
        f16x8 v3 = hv[(size_t)s3 * 8 + fl];
#pragma unroll
        for (int k = 0; k < 8; ++k) acc[k] += m0 * (float)v0[k];
#pragma unroll
        for (int k = 0; k < 8; ++k) acc[k] += m1 * (float)v1[k];
#pragma unroll
        for (int k = 0; k < 8; ++k) acc[k] += m2 * (float)v2[k];
#pragma unroll
        for (int k = 0; k < 8; ++k) acc[k] += m3 * (float)v3[k];
        j += 4;
    }

    float dn = dis[gwc];
    f16x8 hsv = hv[(size_t)gwc * 8 + fl];
    f16x8 o;
#pragma unroll
    for (int k = 0; k < 8; ++k)
        o[k] = (_Float16)((acc[k] + (float)hsv[k]) * dn);
    if (valid)
        __builtin_nontemporal_store(
            o, (f16x8*)(A16 + boff + (size_t)gw * 64 + fl * 8));
}

// ---------------------------------------------------------------------------
// fp16 MFMA GEMM: out = A@W + bias.  A blocked [(K/64)][n][64] fp16;
// W [256][K] fp16; out blocked [4][n][64]. SCALE: out row *= dis[row].
// ---------------------------------------------------------------------------
template <int K, int OUT_RELU, int SCALE>
__global__ __launch_bounds__(256, 2) void k_mgemm(const _Float16* __restrict__ A,
                                                  const _Float16* __restrict__ W,
                                                  const float* __restrict__ bias,
                                                  const float* __restrict__ dis,
                                                  _Float16* __restrict__ outh, int n) {
    __shared__ _Float16 sA[128 * 32];   // 8 KB
    __shared__ _Float16 sW[256 * 32];   // 16 KB

    const int tid = threadIdx.x;
    const int lane = tid & 63;
    const int w = tid >> 6;
    const int c15 = lane & 15;
    const int q = lane >> 4;
    const int row0 = blockIdx.x * 128;
    const size_t bstride = (size_t)n * 64;

    f32x4 acc[8][4];
#pragma unroll
    for (int i = 0; i < 8; ++i)
#pragma unroll
        for (int j = 0; j < 4; ++j) acc[i][j] = (f32x4)0.f;

    for (int kt = 0; kt < K; kt += 32) {
#pragma unroll
        for (int i = 0; i < 2; ++i) {
            int u = tid + (i << 8);
            int row = u >> 2;
            int qq = (u & 3) ^ ((row >> 1) & 3);
            int r = imin(row0 + row, n - 1);
            size_t goff = (size_t)(kt >> 6) * bstride + (size_t)r * 64 + (kt & 63) + qq * 8;
            async16(sA + u * 8, A + goff);
        }
#pragma unroll
        for (int i = 0; i < 4; ++i) {
            int u = tid + (i << 8);
            int c = u >> 2;
            int qq = (u & 3) ^ ((c >> 1) & 3);
            size_t goff = (size_t)c * K + kt + qq * 8;
            async16(sW + u * 8, W + goff);
        }
        __syncthreads();

        f16x8 wf[4];
#pragma unroll
        for (int ct = 0; ct < 4; ++ct) {
            int c = (w << 6) + (ct << 4) + c15;
            int u = (c << 2) + (q ^ ((c >> 1) & 3));
            wf[ct] = *(const f16x8*)(sW + u * 8);
        }
#pragma unroll
        for (int rt = 0; rt < 8; ++rt) {
            int r = (rt << 4) + c15;
            int u = (r << 2) + (q ^ ((r >> 1) & 3));
            f16x8 a = *(const f16x8*)(sA + u * 8);
#pragma unroll
            for (int ct = 0; ct < 4; ++ct)
                acc[rt][ct] = __builtin_amdgcn_mfma_f32_16x16x32_f16(a, wf[ct], acc[rt][ct], 0, 0, 0);
        }
        __syncthreads();
    }

#pragma unroll
    for (int ct = 0; ct < 4; ++ct) {
        int c = (w << 6) + (ct << 4) + c15;
        float bv = bias[c];
        _Float16* ob = outh + (size_t)(c >> 6) * bstride + (c & 63);
#pragma unroll
        for (int rt = 0; rt < 8; ++rt) {
#pragma unroll
            for (int r = 0; r < 4; ++r) {
                int row = row0 + (rt << 4) + (q << 2) + r;
                if (row < n) {
                    float v = acc[rt][ct][r] + bv;
                    if (OUT_RELU) v = fmaxf(v, 0.f);
                    if (SCALE) v *= dis[row];
                    ob[(size_t)row * 64] = (_Float16)v;
                }
            }
        }
    }
}

// ---------------------------------------------------------------------------
// fused head: mean-pool + concat + MLP -> out[b]. one block per graph.
// h blocked [4][N][64].
// ---------------------------------------------------------------------------
__global__ __launch_bounds__(256) void k_head(const _Float16* __restrict__ h,
                                              const int* __restrict__ gstart,
                                              const int* __restrict__ u,
                                              const int* __restrict__ v,
                                              const float* __restrict__ Wm1,
                                              const float* __restrict__ bm1,
                                              const float* __restrict__ Wm2,
                                              const float* __restrict__ bm2,
                                              float* __restrict__ out, int N) {
    int b = blockIdx.x;
    int t = threadIdx.x;
    __shared__ float z[3 * HDIM];
    __shared__ float red[4];
    const _Float16* hb = h + (size_t)(t >> 6) * ((size_t)N * 64) + (t & 63);
    int s = gstart[b], e = gstart[b + 1];
    float pa = 0.f;
    int i = s;
    for (; i + 3 < e; i += 4) {
        float a0 = (float)hb[(size_t)i * 64];
        float a1 = (float)hb[(size_t)(i + 1) * 64];
        float a2 = (float)hb[(size_t)(i + 2) * 64];
        float a3 = (float)hb[(size_t)(i + 3) * 64];
        pa += (a0 + a1) + (a2 + a3);
    }
    for (; i < e; ++i) pa += (float)hb[(size_t)i * 64];
    z[t]            = pa / fmaxf((float)(e - s), 1.f);
    z[HDIM + t]     = (float)hb[(size_t)u[b] * 64];
    z[2 * HDIM + t] = (float)hb[(size_t)v[b] * 64];
    __syncthreads();
    float acc[8];
#pragma unroll
    for (int k = 0; k < 8; ++k) acc[k] = 0.f;
    for (int k = 0; k < 3 * HDIM; k += 8) {
#pragma unroll
        for (int jj = 0; jj < 8; ++jj)
            acc[jj] = fmaf(z[k + jj], Wm1[(size_t)(k + jj) * HDIM + t], acc[jj]);
    }
    float sum = (((acc[0] + acc[1]) + (acc[2] + acc[3])) +
                 ((acc[4] + acc[5]) + (acc[6] + acc[7]))) + bm1[t];
    float hid = fmaxf(sum, 0.f);
    float p = hid * Wm2[t];
    for (int off = 32; off; off >>= 1) p += __shfl_down(p, off);
    if ((t & 63) == 0) red[t >> 6] = p;
    __syncthreads();
    if (t == 0) out[b] = red[0] + red[1] + red[2] + red[3] + bm2[0];
}

// ---------------------------------------------------------------------------
extern "C" void kernel_launch(void* const* d_in, const int* in_sizes, int n_in,
                              void* d_out, int out_size, void* d_ws, size_t ws_size,
                              hipStream_t stream) {
    const float* x    = (const float*)d_in[0];
    const int*   ei   = (const int*)d_in[1];
    const int*   batc = (const int*)d_in[2];
    const int*   uidx = (const int*)d_in[3];
    const int*   vidx = (const int*)d_in[4];
    const float* W0   = (const float*)d_in[5];
    const float* b0   = (const float*)d_in[6];
    const float* W1   = (const float*)d_in[7];
    const float* b1   = (const float*)d_in[8];
    const float* W2   = (const float*)d_in[9];
    const float* b2   = (const float*)d_in[10];
    const float* Wm1  = (const float*)d_in[11];
    const float* bm1  = (const float*)d_in[12];
    const float* Wm2  = (const float*)d_in[13];
    const float* bm2  = (const float*)d_in[14];
    float* out = (float*)d_out;

    const int N = in_sizes[0] / DRNL;
    const int E = in_sizes[1] / 2;
    const int B = in_sizes[3];
    const int* src = ei;
    const int* dst = ei + E;

    int SH = 7;
    while (((N + (1 << SH) - 1) >> SH) > 512) ++SH;
    const int NBUCK = (N + (1 << SH) - 1) >> SH;
    const int P = (E + CHUNK - 1) / CHUNK;

    char* w = (char*)d_ws;
    size_t off = 0;
    auto carve = [&](size_t bytes) {
        void* p = w + off;
        off = (off + bytes + 255) & ~(size_t)255;
        return p;
    };
    int*       rowptr = (int*)carve((size_t)(N + 1) * 4);
    int*       colA   = (int*)carve((size_t)E * 4);
    float*     dis    = (float*)carve((size_t)N * 4);
    int*       gstart = (int*)carve((size_t)(B + 1) * 4);
    _Float16*  A16    = (_Float16*)carve((size_t)N * HDIM * 2);
    _Float16*  h16    = (_Float16*)carve((size_t)N * HDIM * 2);
    _Float16*  x16    = (_Float16*)carve((size_t)N * DRNL * 2);
    _Float16*  W0t    = (_Float16*)carve((size_t)DRNL * HDIM * 2);
    _Float16*  W1t    = (_Float16*)carve((size_t)HDIM * HDIM * 2);
    _Float16*  W2t    = (_Float16*)carve((size_t)HDIM * HDIM * 2);
    int*       ghist  = (int*)carve((size_t)NBUCK * P * 4);
    int*       btot   = (int*)carve(512 * 4);
    int*       bbase  = (int*)carve(513 * 4);
    int*       tmpE   = (int*)carve((size_t)E * 4);
    (void)ws_size;

    // order-independent prep (W transpose, x16 convert, graph bounds)
    k_misc<<<1024, 256, 0, stream>>>(batc, x, W0, W1, W2, gstart,
                                     x16, W0t, W1t, W2t, N, B);
    // atomic-free CSR build (also emits rowptr, dis, and prescales x16)
    k_hist<<<P, 256, 0, stream>>>(dst, ghist, E, P, SH, NBUCK);
    k_gbase<<<NBUCK, 256, 0, stream>>>(ghist, btot, P);
    k_btscan<<<1, 256, 0, stream>>>(btot, bbase, rowptr, NBUCK, N, E);
    k_scatter<<<P, 256, 0, stream>>>(src, dst, ghist, bbase, tmpE, E, P, SH, NBUCK);
    k_bsort<<<NBUCK, 256, 0, stream>>>(tmpE, bbase, colA, rowptr, dis, x16, SH, N);

    int gemmb = (N + 127) / 128;
    int NB = (N + 31) / 32;        // node-WGs (32 nodes each)
    int NH = (NB + 1) / 2;         // node-WGs per XCD-pair half
    int aggb4 = 8 * NH;            // FBLK=4 grid (multiple of 8)

    // layer 0: agg(x') -> GEMM (relu, scale) -> h' blocked-64
    k_agg<1><<<NB, 256, 0, stream>>>(x16, dis, rowptr, colA, A16, N);
    k_mgemm<DRNL, 1, 1><<<gemmb, 256, 0, stream>>>(A16, W0t, b0, dis, h16, N);
    // layer 1: agg(h') -> GEMM (relu, scale) -> h'
    k_agg<4><<<aggb4, 256, 0, stream>>>(h16, dis, rowptr, colA, A16, N);
    k_mgemm<HDIM, 1, 1><<<gemmb, 256, 0, stream>>>(A16, W1t, b1, dis, h16, N);
    // layer 2: agg(h') -> GEMM (no relu, RAW output for head)
    k_agg<4><<<aggb4, 256, 0, stream>>>(h16, dis, rowptr, colA, A16, N);
    k_mgemm<HDIM, 0, 0><<<gemmb, 256, 0, stream>>>(A16, W2t, b2, dis, h16, N);

    // fused mean-pool + MLP head
    k_head<<<B, 256, 0, stream>>>(h16, gstart, uidx, vidx, Wm1, bm1, Wm2, bm2, out, N);
}